// Round 1
// baseline (543.435 us; speedup 1.0000x reference)
//
#include <hip/hip_runtime.h>
#include <hip/hip_bf16.h>

#define T_TOK 16384
#define DM 256
#define NE 8
#define HF 512
#define TM 64

typedef __bf16 bf16x8 __attribute__((ext_vector_type(8)));
typedef float f32x4 __attribute__((ext_vector_type(4)));

__device__ __forceinline__ unsigned short f2bf(float f) {
  unsigned u = __float_as_uint(f);
  u += 0x7fffu + ((u >> 16) & 1u);  // RNE (NaN not expected in this data)
  return (unsigned short)(u >> 16);
}

// ---------------- gate: fp64 scores, top-2 set, append to per-expert lists --------
__global__ __launch_bounds__(256) void gate_kernel(
    const float* __restrict__ x, const float* __restrict__ Wg,
    const float* __restrict__ bg, int* __restrict__ cnts, int* __restrict__ list) {
  int w = threadIdx.x >> 6, lane = threadIdx.x & 63;
  int t = blockIdx.x * 4 + w;
  double acc[NE];
#pragma unroll
  for (int i = 0; i < NE; i++) acc[i] = 0.0;
  const float* xr = x + (size_t)t * DM;
#pragma unroll
  for (int j = 0; j < 4; j++) {
    int d = j * 64 + lane;
    double xv = (double)xr[d];
    const float* wr = Wg + d * NE;
#pragma unroll
    for (int i = 0; i < NE; i++) acc[i] += xv * (double)wr[i];
  }
#pragma unroll
  for (int off = 32; off >= 1; off >>= 1) {
#pragma unroll
    for (int i = 0; i < NE; i++) acc[i] += __shfl_xor(acc[i], off);
  }
  if (lane == 0) {
    double s[NE];
#pragma unroll
    for (int i = 0; i < NE; i++) s[i] = acc[i] + (double)bg[i];
    int e1 = 0;
    for (int i = 1; i < NE; i++) if (s[i] > s[e1]) e1 = i;   // ties -> lower index
    int e2 = -1;
    for (int i = 0; i < NE; i++) {
      if (i == e1) continue;
      if (e2 < 0 || s[i] > s[e2]) e2 = i;
    }
    int p1 = atomicAdd(&cnts[e1], 1); list[e1 * T_TOK + p1] = t;
    int p2 = atomicAdd(&cnts[e2], 1); list[e2 * T_TOK + p2] = t;
  }
}

// ---------------- transpose+cast: in fp32 [R][C] per slab -> out bf16 [C][R] ------
__global__ __launch_bounds__(256) void transpose_kernel(
    const float* __restrict__ in, unsigned short* __restrict__ out, int R, int C) {
  __shared__ float tile[32][33];
  int z = blockIdx.z;
  const float* src = in + (size_t)z * R * C;
  unsigned short* dst = out + (size_t)z * R * C;
  int c0 = blockIdx.x * 32, r0 = blockIdx.y * 32;
  int tx = threadIdx.x, ty = threadIdx.y;  // (32,8)
#pragma unroll
  for (int i = 0; i < 4; i++)
    tile[ty + i * 8][tx] = src[(size_t)(r0 + ty + i * 8) * C + c0 + tx];
  __syncthreads();
#pragma unroll
  for (int i = 0; i < 4; i++)
    dst[(size_t)(c0 + ty + i * 8) * R + r0 + tx] = f2bf(tile[tx][ty + i * 8]);
}

// ---------------- grouped FFN: 64-token tile per block, fused dual GEMM -----------
// w1t: [E][H][D] bf16 (k-contiguous for GEMM1 B-frags)
// w2t: [E][D][H] bf16 (k-contiguous for GEMM2 B-frags)
__global__ __launch_bounds__(256, 2) void ffn_kernel(
    const float* __restrict__ x, const unsigned short* __restrict__ w1t,
    const float* __restrict__ b1, const unsigned short* __restrict__ w2t,
    const float* __restrict__ b2, const int* __restrict__ cnts,
    const int* __restrict__ list, float* __restrict__ out) {
  __shared__ unsigned short Xs[TM][DM + 8];   // 264-elem stride: 16B-aligned rows, bank-skewed
  __shared__ unsigned short Hc[TM][64 + 8];   // h-chunk (gelu output), bf16
  __shared__ int tok[TM];

  int e = blockIdx.x >> 8;
  int tile = blockIdx.x & 255;
  int cnt = cnts[e];
  int base = tile * TM;
  if (base >= cnt) return;
  int rowsv = min(TM, cnt - base);

  int tid = threadIdx.x;
  {  // stage X tile: fp32 -> bf16, gathered rows
    int r = tid >> 2, cg = tid & 3;
    int token = -1;
    if (r < rowsv) token = list[e * T_TOK + base + r];
    if (cg == 0) tok[r] = token;
    if (token >= 0) {
      const float* xr = x + (size_t)token * DM + cg * 64;
#pragma unroll
      for (int j = 0; j < 16; j++) {
        float4 v = *reinterpret_cast<const float4*>(xr + j * 4);
        unsigned long long pk = (unsigned long long)f2bf(v.x) |
                                ((unsigned long long)f2bf(v.y) << 16) |
                                ((unsigned long long)f2bf(v.z) << 32) |
                                ((unsigned long long)f2bf(v.w) << 48);
        *reinterpret_cast<unsigned long long*>(&Xs[r][cg * 64 + j * 4]) = pk;
      }
    } else {
#pragma unroll
      for (int j = 0; j < 16; j++)
        *reinterpret_cast<unsigned long long*>(&Xs[r][cg * 64 + j * 4]) = 0ull;
    }
  }
  __syncthreads();

  int w = tid >> 6, lane = tid & 63;
  int quad = lane >> 4, l16 = lane & 15;

  f32x4 zero4 = {0.f, 0.f, 0.f, 0.f};
  f32x4 oacc[4][4];
#pragma unroll
  for (int mt = 0; mt < 4; mt++)
#pragma unroll
    for (int nt = 0; nt < 4; nt++) oacc[mt][nt] = zero4;

  const unsigned short* w1e = w1t + (size_t)e * HF * DM;
  const unsigned short* w2e = w2t + (size_t)e * DM * HF;

  for (int hc = 0; hc < 8; ++hc) {
    // --- GEMM1: this wave computes Hc cols [w*16, w*16+16) of the 64-col chunk ---
    int n0 = hc * 64 + w * 16;  // absolute h column base
    f32x4 pacc[4];
#pragma unroll
    for (int mt = 0; mt < 4; mt++) pacc[mt] = zero4;
    const unsigned short* bsrc = w1e + (size_t)(n0 + l16) * DM + quad * 8;
#pragma unroll
    for (int ks = 0; ks < 8; ++ks) {
      bf16x8 bfrag = *reinterpret_cast<const bf16x8*>(bsrc + ks * 32);
#pragma unroll
      for (int mt = 0; mt < 4; mt++) {
        bf16x8 afrag =
            *reinterpret_cast<const bf16x8*>(&Xs[mt * 16 + l16][ks * 32 + quad * 8]);
        pacc[mt] = __builtin_amdgcn_mfma_f32_16x16x32_bf16(afrag, bfrag, pacc[mt], 0, 0, 0);
      }
    }
    float bias1 = b1[e * HF + n0 + l16];
#pragma unroll
    for (int mt = 0; mt < 4; mt++) {
#pragma unroll
      for (int r = 0; r < 4; r++) {
        float v = pacc[mt][r] + bias1;
        float g = 0.5f * v * (1.0f + erff(v * 0.70710678118654752f));  // exact gelu
        Hc[mt * 16 + quad * 4 + r][w * 16 + l16] = f2bf(g);
      }
    }
    __syncthreads();
    // --- GEMM2 partial: oacc += Hc @ W2[hc-chunk, this wave's 64 d-cols] ---
#pragma unroll
    for (int ks2 = 0; ks2 < 2; ++ks2) {
      bf16x8 af[4];
#pragma unroll
      for (int mt = 0; mt < 4; mt++)
        af[mt] = *reinterpret_cast<const bf16x8*>(&Hc[mt * 16 + l16][ks2 * 32 + quad * 8]);
#pragma unroll
      for (int nt = 0; nt < 4; nt++) {
        int d = w * 64 + nt * 16 + l16;
        bf16x8 bfrag = *reinterpret_cast<const bf16x8*>(
            w2e + (size_t)d * HF + hc * 64 + ks2 * 32 + quad * 8);
#pragma unroll
        for (int mt = 0; mt < 4; mt++)
          oacc[mt][nt] =
              __builtin_amdgcn_mfma_f32_16x16x32_bf16(af[mt], bfrag, oacc[mt][nt], 0, 0, 0);
      }
    }
    __syncthreads();  // Hc reused next chunk
  }

  // --- epilogue: scatter-add contributions (+b2 per expert hit) ---
#pragma unroll
  for (int mt = 0; mt < 4; mt++) {
#pragma unroll
    for (int r = 0; r < 4; r++) {
      int m = mt * 16 + quad * 4 + r;
      int token = tok[m];
      if (token < 0) continue;
      float* orow = out + (size_t)token * DM;
#pragma unroll
      for (int nt = 0; nt < 4; nt++) {
        int d = w * 64 + nt * 16 + l16;
        atomicAdd(&orow[d], oacc[mt][nt][r] + b2[e * DM + d]);
      }
    }
  }
}

extern "C" void kernel_launch(void* const* d_in, const int* in_sizes, int n_in,
                              void* d_out, int out_size, void* d_ws, size_t ws_size,
                              hipStream_t stream) {
  (void)in_sizes; (void)n_in; (void)ws_size;
  const float* x  = (const float*)d_in[0];
  const float* Wg = (const float*)d_in[1];
  const float* bg = (const float*)d_in[2];
  const float* W1 = (const float*)d_in[3];
  const float* b1 = (const float*)d_in[4];
  const float* W2 = (const float*)d_in[5];
  const float* b2 = (const float*)d_in[6];
  float* out = (float*)d_out;

  char* ws = (char*)d_ws;
  int* cnts = (int*)ws;                                      // 256 B (8 used)
  int* list = (int*)(ws + 256);                              // 8*16384*4 = 512 KB
  unsigned short* w1t = (unsigned short*)(ws + 256 + 524288);            // 2 MB
  unsigned short* w2t = (unsigned short*)(ws + 256 + 524288 + 2097152);  // 2 MB

  hipMemsetAsync(cnts, 0, 256, stream);
  hipMemsetAsync(d_out, 0, (size_t)out_size * sizeof(float), stream);

  dim3 tb(32, 8);
  // W1: per-expert [D=256][H=512] -> w1t [H][D]
  hipLaunchKernelGGL(transpose_kernel, dim3(HF / 32, DM / 32, NE), tb, 0, stream,
                     W1, w1t, DM, HF);
  // W2: per-expert [H=512][D=256] -> w2t [D][H]
  hipLaunchKernelGGL(transpose_kernel, dim3(DM / 32, HF / 32, NE), tb, 0, stream,
                     W2, w2t, HF, DM);
  hipLaunchKernelGGL(gate_kernel, dim3(T_TOK / 4), dim3(256), 0, stream,
                     x, Wg, bg, cnts, list);
  hipLaunchKernelGGL(ffn_kernel, dim3(NE * 256), dim3(256), 0, stream,
                     x, w1t, b1, w2t, b2, cnts, list, out);
}

// Round 2
// 188.574 us; speedup vs baseline: 2.8818x; 2.8818x over previous
//
#include <hip/hip_runtime.h>
#include <hip/hip_bf16.h>

#define T_TOK 16384
#define DM 256
#define NE 8
#define HF 512
#define TM 64

typedef __bf16 bf16x8 __attribute__((ext_vector_type(8)));
typedef float f32x4 __attribute__((ext_vector_type(4)));

__device__ __forceinline__ unsigned short f2bf(float f) {
  unsigned u = __float_as_uint(f);
  u += 0x7fffu + ((u >> 16) & 1u);  // RNE (NaN not expected in this data)
  return (unsigned short)(u >> 16);
}

// ---------------- gate: thread-per-token fp64 top-2 + block-aggregated list build --
__global__ __launch_bounds__(256) void gate_kernel(
    const float* __restrict__ x, const float* __restrict__ Wg,
    const float* __restrict__ bg, int* __restrict__ cnts, int* __restrict__ list) {
  __shared__ float wg_s[DM * NE];  // 8 KB
  __shared__ int hist[NE], base_s[NE], rank[NE];
  int tid = threadIdx.x;
#pragma unroll
  for (int i = 0; i < NE; i++) wg_s[tid * NE + i] = Wg[tid * NE + i];  // 256 rows, 1 per thread
  if (tid < NE) { hist[tid] = 0; rank[tid] = 0; }
  __syncthreads();

  int t = blockIdx.x * 256 + tid;
  const float* xr = x + (size_t)t * DM;
  double acc[NE];
#pragma unroll
  for (int i = 0; i < NE; i++) acc[i] = (double)bg[i];
  for (int d = 0; d < DM; d += 4) {
    float4 xv = *reinterpret_cast<const float4*>(xr + d);
    const float* w0 = &wg_s[d * NE];
#pragma unroll
    for (int i = 0; i < NE; i++) {
      acc[i] += (double)xv.x * (double)w0[i] + (double)xv.y * (double)w0[NE + i] +
                (double)xv.z * (double)w0[2 * NE + i] + (double)xv.w * (double)w0[3 * NE + i];
    }
  }
  int e1 = 0;
#pragma unroll
  for (int i = 1; i < NE; i++) if (acc[i] > acc[e1]) e1 = i;  // ties -> lower index
  int e2 = -1;
#pragma unroll
  for (int i = 0; i < NE; i++) {
    if (i == e1) continue;
    if (e2 < 0 || acc[i] > acc[e2]) e2 = i;
  }

  atomicAdd(&hist[e1], 1);
  atomicAdd(&hist[e2], 1);
  __syncthreads();
  if (tid < NE) base_s[tid] = atomicAdd(&cnts[tid], hist[tid]);  // 8 global atomics/block
  __syncthreads();
  int r1 = atomicAdd(&rank[e1], 1);
  list[e1 * T_TOK + base_s[e1] + r1] = t;
  int r2 = atomicAdd(&rank[e2], 1);
  list[e2 * T_TOK + base_s[e2] + r2] = t;
}

// ---------------- transpose+cast: in fp32 [R][C] per slab -> out bf16 [C][R] ------
__global__ __launch_bounds__(256) void transpose_kernel(
    const float* __restrict__ in, unsigned short* __restrict__ out, int R, int C) {
  __shared__ float tile[32][33];
  int z = blockIdx.z;
  const float* src = in + (size_t)z * R * C;
  unsigned short* dst = out + (size_t)z * R * C;
  int c0 = blockIdx.x * 32, r0 = blockIdx.y * 32;
  int tx = threadIdx.x, ty = threadIdx.y;  // (32,8)
#pragma unroll
  for (int i = 0; i < 4; i++)
    tile[ty + i * 8][tx] = src[(size_t)(r0 + ty + i * 8) * C + c0 + tx];
  __syncthreads();
#pragma unroll
  for (int i = 0; i < 4; i++)
    dst[(size_t)(c0 + ty + i * 8) * R + r0 + tx] = f2bf(tile[tx][ty + i * 8]);
}

// ---------------- grouped FFN: 64-token tile per block, fused dual GEMM -----------
// w1t: [E][H][D] bf16 (k-contiguous for GEMM1 B-frags)
// w2t: [E][D][H] bf16 (k-contiguous for GEMM2 B-frags)
__global__ __launch_bounds__(256, 2) void ffn_kernel(
    const float* __restrict__ x, const unsigned short* __restrict__ w1t,
    const float* __restrict__ b1, const unsigned short* __restrict__ w2t,
    const float* __restrict__ b2, const int* __restrict__ cnts,
    const int* __restrict__ list, float* __restrict__ out) {
  __shared__ unsigned short Xs[TM][DM + 8];   // 264-elem stride: 16B-aligned rows, bank-skewed
  __shared__ unsigned short Hc[TM][64 + 8];   // h-chunk (gelu output), bf16
  __shared__ int tok[TM];

  int e = blockIdx.x >> 8;
  int tile = blockIdx.x & 255;
  int cnt = cnts[e];
  int base = tile * TM;
  if (base >= cnt) return;
  int rowsv = min(TM, cnt - base);

  int tid = threadIdx.x;
  {  // stage X tile: fp32 -> bf16, gathered rows
    int r = tid >> 2, cg = tid & 3;
    int token = -1;
    if (r < rowsv) token = list[e * T_TOK + base + r];
    if (cg == 0) tok[r] = token;
    if (token >= 0) {
      const float* xr = x + (size_t)token * DM + cg * 64;
#pragma unroll
      for (int j = 0; j < 16; j++) {
        float4 v = *reinterpret_cast<const float4*>(xr + j * 4);
        unsigned long long pk = (unsigned long long)f2bf(v.x) |
                                ((unsigned long long)f2bf(v.y) << 16) |
                                ((unsigned long long)f2bf(v.z) << 32) |
                                ((unsigned long long)f2bf(v.w) << 48);
        *reinterpret_cast<unsigned long long*>(&Xs[r][cg * 64 + j * 4]) = pk;
      }
    } else {
#pragma unroll
      for (int j = 0; j < 16; j++)
        *reinterpret_cast<unsigned long long*>(&Xs[r][cg * 64 + j * 4]) = 0ull;
    }
  }
  __syncthreads();

  int w = tid >> 6, lane = tid & 63;
  int quad = lane >> 4, l16 = lane & 15;

  f32x4 zero4 = {0.f, 0.f, 0.f, 0.f};
  f32x4 oacc[4][4];
#pragma unroll
  for (int mt = 0; mt < 4; mt++)
#pragma unroll
    for (int nt = 0; nt < 4; nt++) oacc[mt][nt] = zero4;

  const unsigned short* w1e = w1t + (size_t)e * HF * DM;
  const unsigned short* w2e = w2t + (size_t)e * DM * HF;

  for (int hc = 0; hc < 8; ++hc) {
    // --- GEMM1: this wave computes Hc cols [w*16, w*16+16) of the 64-col chunk ---
    int n0 = hc * 64 + w * 16;  // absolute h column base
    f32x4 pacc[4];
#pragma unroll
    for (int mt = 0; mt < 4; mt++) pacc[mt] = zero4;
    const unsigned short* bsrc = w1e + (size_t)(n0 + l16) * DM + quad * 8;
#pragma unroll
    for (int ks = 0; ks < 8; ++ks) {
      bf16x8 bfrag = *reinterpret_cast<const bf16x8*>(bsrc + ks * 32);
#pragma unroll
      for (int mt = 0; mt < 4; mt++) {
        bf16x8 afrag =
            *reinterpret_cast<const bf16x8*>(&Xs[mt * 16 + l16][ks * 32 + quad * 8]);
        pacc[mt] = __builtin_amdgcn_mfma_f32_16x16x32_bf16(afrag, bfrag, pacc[mt], 0, 0, 0);
      }
    }
    float bias1 = b1[e * HF + n0 + l16];
#pragma unroll
    for (int mt = 0; mt < 4; mt++) {
#pragma unroll
      for (int r = 0; r < 4; r++) {
        float v = pacc[mt][r] + bias1;
        float g = 0.5f * v * (1.0f + erff(v * 0.70710678118654752f));  // exact gelu
        Hc[mt * 16 + quad * 4 + r][w * 16 + l16] = f2bf(g);
      }
    }
    __syncthreads();
    // --- GEMM2 partial: oacc += Hc @ W2[hc-chunk, this wave's 64 d-cols] ---
#pragma unroll
    for (int ks2 = 0; ks2 < 2; ++ks2) {
      bf16x8 af[4];
#pragma unroll
      for (int mt = 0; mt < 4; mt++)
        af[mt] = *reinterpret_cast<const bf16x8*>(&Hc[mt * 16 + l16][ks2 * 32 + quad * 8]);
#pragma unroll
      for (int nt = 0; nt < 4; nt++) {
        int d = w * 64 + nt * 16 + l16;
        bf16x8 bfrag = *reinterpret_cast<const bf16x8*>(
            w2e + (size_t)d * HF + hc * 64 + ks2 * 32 + quad * 8);
#pragma unroll
        for (int mt = 0; mt < 4; mt++)
          oacc[mt][nt] =
              __builtin_amdgcn_mfma_f32_16x16x32_bf16(af[mt], bfrag, oacc[mt][nt], 0, 0, 0);
      }
    }
    __syncthreads();  // Hc reused next chunk
  }

  // --- epilogue: scatter-add contributions (+b2 per expert hit) ---
#pragma unroll
  for (int mt = 0; mt < 4; mt++) {
#pragma unroll
    for (int r = 0; r < 4; r++) {
      int m = mt * 16 + quad * 4 + r;
      int token = tok[m];
      if (token < 0) continue;
      float* orow = out + (size_t)token * DM;
#pragma unroll
      for (int nt = 0; nt < 4; nt++) {
        int d = w * 64 + nt * 16 + l16;
        atomicAdd(&orow[d], oacc[mt][nt][r] + b2[e * DM + d]);
      }
    }
  }
}

extern "C" void kernel_launch(void* const* d_in, const int* in_sizes, int n_in,
                              void* d_out, int out_size, void* d_ws, size_t ws_size,
                              hipStream_t stream) {
  (void)in_sizes; (void)n_in; (void)ws_size;
  const float* x  = (const float*)d_in[0];
  const float* Wg = (const float*)d_in[1];
  const float* bg = (const float*)d_in[2];
  const float* W1 = (const float*)d_in[3];
  const float* b1 = (const float*)d_in[4];
  const float* W2 = (const float*)d_in[5];
  const float* b2 = (const float*)d_in[6];
  float* out = (float*)d_out;

  char* ws = (char*)d_ws;
  int* cnts = (int*)ws;                                      // 256 B (8 used)
  int* list = (int*)(ws + 256);                              // 8*16384*4 = 512 KB
  unsigned short* w1t = (unsigned short*)(ws + 256 + 524288);            // 2 MB
  unsigned short* w2t = (unsigned short*)(ws + 256 + 524288 + 2097152);  // 2 MB

  hipMemsetAsync(cnts, 0, 256, stream);
  hipMemsetAsync(d_out, 0, (size_t)out_size * sizeof(float), stream);

  dim3 tb(32, 8);
  // W1: per-expert [D=256][H=512] -> w1t [H][D]
  hipLaunchKernelGGL(transpose_kernel, dim3(HF / 32, DM / 32, NE), tb, 0, stream,
                     W1, w1t, DM, HF);
  // W2: per-expert [H=512][D=256] -> w2t [D][H]
  hipLaunchKernelGGL(transpose_kernel, dim3(DM / 32, HF / 32, NE), tb, 0, stream,
                     W2, w2t, HF, DM);
  hipLaunchKernelGGL(gate_kernel, dim3(T_TOK / 256), dim3(256), 0, stream,
                     x, Wg, bg, cnts, list);
  hipLaunchKernelGGL(ffn_kernel, dim3(NE * 256), dim3(256), 0, stream,
                     x, w1t, b1, w2t, b2, cnts, list, out);
}